// Round 10
// baseline (741.665 us; speedup 1.0000x reference)
//
#include <hip/hip_runtime.h>
#include <hip/hip_bf16.h>

#define BB   8
#define HH   64
#define WWID 64
#define CC   384
#define FF   1536
#define EE   8
#define LL   256
#define MTOTMAX 67584   // 65536 real rows + 8*256 max padding (256-aligned experts)
#define NTMAX   264     // MTOTMAX/256

typedef unsigned short ushort_t;
typedef __attribute__((ext_vector_type(4))) unsigned short u16x4;
typedef __attribute__((ext_vector_type(8))) short          s16x8;  // 8 bf16 = 16B
typedef __attribute__((ext_vector_type(4))) float          f32x4;

__device__ __forceinline__ float bf2f(ushort_t u) {
  union { unsigned int i; float f; } v; v.i = ((unsigned int)u) << 16; return v.f;
}
__device__ __forceinline__ ushort_t f2bf(float f) {
  union { float f; unsigned int i; } v; v.f = f;
  unsigned int u = v.i;
  u += 0x7fffu + ((u >> 16) & 1u);
  return (ushort_t)(u >> 16);
}
// gelu via tanh-form sigmoid, constants folded into one fma (proven r2/r6):
//   gelu(x) ~= x * rcp(1 + exp2(x * (-2.3022082 - 0.10294325 x^2)))
__device__ __forceinline__ float gelu_f(float x) {
  float x2 = x * x;
  float t  = __builtin_fmaf(x2, -0.10294325f, -2.3022082f);
  float e  = __builtin_amdgcn_exp2f(x * t);
  float r  = __builtin_amdgcn_rcpf(1.0f + e);
  return x * r;
}

// async 16B/lane global->LDS; LDS dest = wave-uniform base + lane*16
#define GLDS(g, l) __builtin_amdgcn_global_load_lds( \
    (const __attribute__((address_space(1))) void*)(g), \
    (__attribute__((address_space(3))) void*)(l), 16, 0, 0)

// ---------------------------------------------------------------------------
// Transpose+cast: src f32 [E][R][Cd] -> dst bf16 [E][Cd][R]
// ---------------------------------------------------------------------------
__global__ __launch_bounds__(256) void k_transpose(const float* __restrict__ src,
                                                   ushort_t* __restrict__ dst,
                                                   int R, int Cd) {
  __shared__ ushort_t tile[32][33];
  int e  = blockIdx.z;
  int c0 = blockIdx.x * 32, r0 = blockIdx.y * 32;
  int tx = threadIdx.x & 31, ty = threadIdx.x >> 5;
  const float* s = src + (size_t)e * R * Cd;
  ushort_t*    d = dst + (size_t)e * R * Cd;
  #pragma unroll
  for (int i = 0; i < 32; i += 8)
    tile[ty + i][tx] = f2bf(s[(size_t)(r0 + ty + i) * Cd + c0 + tx]);
  __syncthreads();
  #pragma unroll
  for (int i = 0; i < 32; i += 8)
    d[(size_t)(c0 + ty + i) * R + r0 + tx] = tile[tx][ty + i];
}

// ---------------------------------------------------------------------------
// gw transpose: [E][C][16] f32 -> gwt [E][16][C] f32
// ---------------------------------------------------------------------------
__global__ void k_tgw(const float* __restrict__ gw, float* __restrict__ gwt) {
  int e = blockIdx.x, t = threadIdx.x;
  for (int i = t; i < CC * 16; i += 256) {
    int c = i >> 4, p = i & 15;
    gwt[((size_t)e * 16 + p) * CC + c] = gw[(size_t)e * CC * 16 + i];
  }
}

// ---------------------------------------------------------------------------
// Router: one block per (b, conv-patch l2); coalesced f32x4; softmax -> top2.
// ---------------------------------------------------------------------------
__global__ __launch_bounds__(256) void k_router(const float* __restrict__ x,
                                                const float* __restrict__ gwt,
                                                int* __restrict__ re, float* __restrict__ rw,
                                                int* __restrict__ cnt) {
  int bid = blockIdx.x;                 // b*256 + l2
  int b = bid >> 8, l2 = bid & 255;
  int hp = l2 >> 4, wp = l2 & 15;
  int t = threadIdx.x;
  int e = t >> 5, lane = t & 31;
  const float* xb = x + (size_t)b * (HH * WWID) * CC;
  const float* ge = gwt + (size_t)e * 16 * CC;
  float acc = 0.f;
  #pragma unroll
  for (int p = 0; p < 16; ++p) {
    int pix = (hp * 4 + (p >> 2)) * 64 + wp * 4 + (p & 3);
    const float* xr = xb + (size_t)pix * CC;
    const float* gr = ge + (size_t)p * CC;
    #pragma unroll
    for (int it = 0; it < 3; ++it) {
      f32x4 xv = *reinterpret_cast<const f32x4*>(xr + it * 128 + lane * 4);
      f32x4 gv = *reinterpret_cast<const f32x4*>(gr + it * 128 + lane * 4);
      acc += xv.x * gv.x + xv.y * gv.y + xv.z * gv.z + xv.w * gv.w;
    }
  }
  #pragma unroll
  for (int d = 16; d; d >>= 1) acc += __shfl_down(acc, d, 32);
  __shared__ float logits[EE];
  if (lane == 0) logits[e] = acc;
  __syncthreads();
  if (t == 0) {
    float m = logits[0];
    #pragma unroll
    for (int i = 1; i < EE; ++i) m = fmaxf(m, logits[i]);
    float p[EE]; float s = 0.f;
    #pragma unroll
    for (int i = 0; i < EE; ++i) { p[i] = __expf(logits[i] - m); s += p[i]; }
    #pragma unroll
    for (int i = 0; i < EE; ++i) p[i] /= s;
    int e0 = 0;
    #pragma unroll
    for (int i = 1; i < EE; ++i) if (p[i] > p[e0]) e0 = i;
    int e1 = (e0 == 0) ? 1 : 0;
    #pragma unroll
    for (int i = 0; i < EE; ++i) if (i != e0 && p[i] > p[e1]) e1 = i;
    float s2 = p[e0] + p[e1] + 1e-9f;
    re[bid * 2 + 0] = e0;  re[bid * 2 + 1] = e1;
    rw[bid * 2 + 0] = p[e0] / s2;  rw[bid * 2 + 1] = p[e1] / s2;
    atomicAdd(&cnt[e0], 16);
    atomicAdd(&cnt[e1], 16);
  }
}

// ---------------------------------------------------------------------------
// Pad/prefix (parallel).  Experts padded to 256-row multiples (256-m tiles).
// ---------------------------------------------------------------------------
__global__ void k_pad(const int* __restrict__ cnt, int* __restrict__ cntp,
                      int* __restrict__ basep, int* __restrict__ tile2e,
                      int* __restrict__ gids, float* __restrict__ gwts) {
  __shared__ int s_cnt[EE], s_cntp[EE], s_base[EE + 1];
  int t = threadIdx.x;
  if (t == 0) {
    int b = 0;
    for (int e = 0; e < EE; ++e) {
      int c  = cnt[e];
      int cp = (c + 255) & ~255;
      s_cnt[e] = c; s_cntp[e] = cp; s_base[e] = b;
      b += cp;
    }
    s_base[EE] = b;
  }
  __syncthreads();
  if (t < EE) { cntp[t] = s_cntp[t]; basep[t] = s_base[t]; }
  if (t == EE) basep[EE] = s_base[EE];
  int ntot = s_base[EE] >> 8;          // 256-row tiles
  for (int g = t; g < ntot; g += 256) {
    int e = 0;
    #pragma unroll
    for (int i = 1; i < EE; ++i) if (g * 256 >= s_base[i]) e = i;
    tile2e[g] = e;
  }
  for (int e = 0; e < EE; ++e)
    for (int i = s_cnt[e] + t; i < s_cntp[e]; i += 256) {
      gids[s_base[e] + i] = -1;
      gwts[s_base[e] + i] = 0.f;
    }
}

// ---------------------------------------------------------------------------
// Assign: one thread per (patch,slot); 16 pixel rows into compacted gids/gwts
// AND inverse map inv[slot*32768+pix] = global padded row.
// ---------------------------------------------------------------------------
__global__ void k_assign(const int* __restrict__ re, const float* __restrict__ rw,
                         const int* __restrict__ basep, int* __restrict__ cnt2,
                         int* __restrict__ gids, float* __restrict__ gwts,
                         int* __restrict__ inv) {
  int i = blockIdx.x * blockDim.x + threadIdx.x;   // patch*2 + slot
  if (i >= BB * LL * 2) return;
  int pat = i >> 1, slot = i & 1;
  int b = pat >> 8, l2 = pat & 255;
  int e = re[i];
  float w = rw[i];
  int t2 = l2 >> 4, hp = l2 & 15;
  int kh = t2 >> 2, kw = t2 & 3;
  int h = hp * 4 + kh;
  int row = basep[e] + atomicAdd(&cnt2[e], 16);
  #pragma unroll
  for (int j = 0; j < 16; ++j) {
    int wpix = j * 4 + kw;
    int pix = (b << 12) + (h << 6) + wpix;
    gids[row + j] = pix;
    gwts[row + j] = w;
    inv[(slot << 15) + pix] = row + j;
  }
}

// ---------------------------------------------------------------------------
// Gather chunk: x f32 rows -> Xc bf16 [local row][CC]; t0 = pass base in
// 128-row blocks.
// ---------------------------------------------------------------------------
__global__ __launch_bounds__(256) void k_gather(const float* __restrict__ x,
                                                const int* __restrict__ gids,
                                                const int* __restrict__ basep,
                                                ushort_t* __restrict__ Xc, int t0) {
  int g = t0 + blockIdx.x;
  if (g * 128 >= basep[EE]) return;
  __shared__ int s_id[128];
  int t = threadIdx.x;
  if (t < 128) s_id[t] = gids[g * 128 + t];
  __syncthreads();
  ushort_t* dst = Xc + (size_t)blockIdx.x * 128 * CC;
  for (int i = t; i < 128 * 96; i += 256) {
    int row = i / 96, ch = (i % 96) * 4;
    int id = s_id[row];
    f32x4 v = (f32x4){0.f, 0.f, 0.f, 0.f};
    if (id >= 0) v = *reinterpret_cast<const f32x4*>(x + (size_t)(id & 32767) * CC + ch);
    u16x4 o = {f2bf(v.x), f2bf(v.y), f2bf(v.z), f2bf(v.w)};
    *reinterpret_cast<u16x4*>(dst + (size_t)row * CC + ch) = o;
  }
}

// ---------------------------------------------------------------------------
// Unified GEMM, 256-row M-tile x TN-col N-tile, 8 waves (512 thr).
//   r6/r7/r9: TN=256 gemm1 / TN=128 gemm2; staging-rate-bound (~5.4TB/s
//   effective) with gemm2 grid-starved at 1.5 blocks/CU in 2-pass mode.
//   This round: single-pass (y aliased over dead Xc) if ws fits ->
//   gemm2 792 blocks (3.1/CU), gemm1 1584; else dynamic max-chunk.
// Schedule: r2/r6-PROVEN two-barrier double-buffer, counted vmcnt.
// ---------------------------------------------------------------------------
#define STAGE(DST, KOFF)                                                      \
  { _Pragma("unroll")                                                         \
    for (int c = 0; c < NC; ++c)                                              \
      GLDS(src_c[c] + (KOFF), (DST) + (w * NC + c) * 512); }

#define PHASE(VMFULL, RD, DOST, KOFF)                                         \
  {                                                                           \
    if (VMFULL) {                                                             \
      if constexpr (NC == 4) { asm volatile("s_waitcnt vmcnt(4)" ::: "memory"); } \
      else                   { asm volatile("s_waitcnt vmcnt(3)" ::: "memory"); } \
    } else {                                                                  \
      asm volatile("s_waitcnt vmcnt(0)" ::: "memory");                        \
    }                                                                         \
    __builtin_amdgcn_s_barrier();                                             \
    __builtin_amdgcn_sched_barrier(0);                                        \
    s16x8 af[FI], bf[4];                                                      \
    _Pragma("unroll")                                                         \
    for (int i = 0; i < FI; ++i)                                              \
      af[i] = *reinterpret_cast<const s16x8*>((RD) + (wf * FI + i) * 512 + lane * 8); \
    _Pragma("unroll")                                                         \
    for (int j = 0; j < 4; ++j)                                               \
      bf[j] = *reinterpret_cast<const s16x8*>((RD) + (2 * FI + wm * 4 + j) * 512 + lane * 8); \
    asm volatile("s_waitcnt lgkmcnt(0)" ::: "memory");                        \
    __builtin_amdgcn_sched_barrier(0);                                        \
    __builtin_amdgcn_s_barrier();                                             \
    if (DOST) STAGE(RD, KOFF);                                                \
    __builtin_amdgcn_s_setprio(1);                                            \
    _Pragma("unroll")                                                         \
    for (int i = 0; i < FI; ++i)                                              \
      _Pragma("unroll")                                                       \
      for (int j = 0; j < 4; ++j)                                             \
        acc[i][j] = __builtin_amdgcn_mfma_f32_16x16x32_bf16(af[i], bf[j], acc[i][j], 0, 0, 0); \
    __builtin_amdgcn_s_setprio(0);                                            \
  }

template<int K, int NOUT, int TN, bool GELU, bool OUTG>
__global__ __launch_bounds__(512, 2) void k_gemm(const ushort_t* __restrict__ A,
                                                 const ushort_t* __restrict__ Bsrc,
                                                 const float* __restrict__ bias,
                                                 const int* __restrict__ basep,
                                                 const int* __restrict__ tile2e,
                                                 const float* __restrict__ gwts,
                                                 ushort_t* __restrict__ out, int t0) {
  constexpr int FI  = TN / 32;          // n-subtiles per wave
  constexpr int NCH = 2 * FI + 16;      // LDS chunks per buffer (A + B)
  constexpr int NC  = NCH / 8;          // GLDS per wave per phase
  constexpr int NX  = NOUT / TN;
  // bijective XCD swizzle (contiguous chunk per XCD); guarded for nwg%8!=0
  int nwg = NX * (int)gridDim.y;
  int wg  = (int)blockIdx.y * NX + (int)blockIdx.x;
  int id  = ((nwg & 7) == 0) ? ((wg & 7) * (nwg >> 3) + (wg >> 3)) : wg;
  int ng  = id % NX;                    // n-group (TN cols)
  int ly  = id / NX;                    // local 256-row tile
  int g   = t0 + ly;                    // global 256-row tile
  if (g * 256 >= basep[EE]) return;
  int e = tile2e[g];
  __shared__ ushort_t S[2][NCH * 512];
  int t = threadIdx.x, w = t >> 6, lane = t & 63;
  int l15 = lane & 15, q = lane >> 4;
  int wf = w & 1, wm = w >> 1;          // n-half, m-quarter
  const ushort_t* a_src = A + ((size_t)e * NOUT + ng * TN) * K;
  const ushort_t* b_src = Bsrc + (size_t)ly * 256 * K;

  const ushort_t* src_c[NC];
  #pragma unroll
  for (int c = 0; c < NC; ++c) {
    int ch = w * NC + c;
    src_c[c] = (ch < 2 * FI)
      ? a_src + (size_t)(ch * 16 + l15) * K + q * 8
      : b_src + (size_t)((ch - 2 * FI) * 16 + l15) * K + q * 8;
  }

  f32x4 acc[FI][4];
  #pragma unroll
  for (int i = 0; i < FI; ++i)
    #pragma unroll
    for (int j = 0; j < 4; ++j) acc[i][j] = (f32x4){0.f, 0.f, 0.f, 0.f};

  ushort_t* S0 = &S[0][0];
  ushort_t* S1 = &S[1][0];

  STAGE(S0, 0);
  STAGE(S1, 32);

  constexpr int NIT = K / 32;           // even (12 or 48)
  for (int it = 0; it < NIT - 2; it += 2) {
    PHASE(true, S0, true, (size_t)(it + 2) * 32);
    PHASE(true, S1, true, (size_t)(it + 3) * 32);
  }
  PHASE(true,  S0, false, 0);
  PHASE(false, S1, false, 0);

  // epilogue
  int nb = ng * TN + wf * (TN / 2) + q * 4;     // + i*16 + r -> output col
  f32x4 bv[FI];
  #pragma unroll
  for (int i = 0; i < FI; ++i)
    bv[i] = *reinterpret_cast<const f32x4*>(bias + (size_t)e * NOUT + nb + i * 16);
  ushort_t* ob = out + (OUTG ? (size_t)g : (size_t)ly) * 256 * NOUT;
  #pragma unroll
  for (int j = 0; j < 4; ++j) {
    int m = wm * 64 + j * 16 + l15;
    float wt = GELU ? 1.f : gwts[g * 256 + m];
    ushort_t* op = ob + (size_t)m * NOUT + nb;
    #pragma unroll
    for (int i = 0; i < FI; ++i) {
      u16x4 v;
      #pragma unroll
      for (int r = 0; r < 4; ++r) {
        float xv = acc[i][j][r] + bv[i][r];
        v[r] = f2bf(GELU ? gelu_f(xv) : xv * wt);
      }
      *reinterpret_cast<u16x4*>(op + i * 16) = v;
    }
  }
}

// ---------------------------------------------------------------------------
// Finalize: out[b][h][c][w] = y_c[inv0[pix]][c] + y_c[inv1[pix]][c]
// ---------------------------------------------------------------------------
__global__ __launch_bounds__(256) void k_final(const ushort_t* __restrict__ y,
                                               const int* __restrict__ inv,
                                               float* __restrict__ out) {
  int bid = blockIdx.x;                 // b*64 + h
  __shared__ float tile[64][193];
  __shared__ int s_r0[64], s_r1[64];
  int t = threadIdx.x;
  if (t < 64) {
    s_r0[t] = inv[(bid << 6) + t];
    s_r1[t] = inv[32768 + (bid << 6) + t];
  }
  __syncthreads();
  float* dst = out + (size_t)bid * CC * WWID;   // [c][w]
  #pragma unroll
  for (int half = 0; half < 2; ++half) {
    int c0 = half * 192;
    for (int i = t; i < 64 * 48; i += 256) {
      int w = i / 48, c4 = (i % 48) * 4;
      u16x4 a = *reinterpret_cast<const u16x4*>(y + (size_t)s_r0[w] * CC + c0 + c4);
      u16x4 b = *reinterpret_cast<const u16x4*>(y + (size_t)s_r1[w] * CC + c0 + c4);
      #pragma unroll
      for (int k = 0; k < 4; ++k)
        tile[w][c4 + k] = bf2f(a[k]) + bf2f(b[k]);
    }
    __syncthreads();
    for (int i = t; i < 64 * 192; i += 256) {
      int cl = i / 64, w = i % 64;
      dst[(size_t)(c0 + cl) * WWID + w] = tile[w][cl];
    }
    __syncthreads();
  }
}

// ---------------------------------------------------------------------------
extern "C" void kernel_launch(void* const* d_in, const int* in_sizes, int n_in,
                              void* d_out, int out_size, void* d_ws, size_t ws_size,
                              hipStream_t stream) {
  const float* x  = (const float*)d_in[0];
  const float* gw = (const float*)d_in[1];
  const float* w1 = (const float*)d_in[2];
  const float* b1 = (const float*)d_in[3];
  const float* w2 = (const float*)d_in[4];
  const float* b2 = (const float*)d_in[5];

  // fixed buffers excluding Xc / Hc / y
  const size_t fixed_nb = (size_t)EE * FF * CC * 2 * 2   // w1t, w2t
                        + (size_t)EE * 16 * CC * 4        // gwt
                        + (size_t)MTOTMAX * 4 * 2         // gids,gwts
                        + (size_t)65536 * 4               // inv
                        + (size_t)BB * LL * 2 * 4 * 2     // re, rw
                        + (size_t)NTMAX * 4               // tile2e
                        + 1024;

  // Single-pass with y aliased over dead Xc (identical rows x 384 bf16
  // layout; strict stream order gather->gemm1->gemm2->final, no overlap):
  // needs exactly Xc(=y) 768B/row + Hc 3072B/row at MTOTMAX rows.
  const bool single = fixed_nb + (size_t)MTOTMAX * 3840 <= ws_size;

  int MC;
  if (single) {
    MC = MTOTMAX;
  } else {
    // dynamic max chunk with separate y buffer
    const size_t fixed2 = fixed_nb + (size_t)MTOTMAX * CC * 2;   // + y
    size_t avail = (ws_size > fixed2) ? (ws_size - fixed2) : 0;
    MC = (int)(avail / 3840) & ~255;
    if (MC < 1024) MC = 1024;
    if (MC > MTOTMAX) MC = MTOTMAX;
  }
  const int npass = (MTOTMAX + MC - 1) / MC;
  const int nt128 = MC / 128;
  const int nt256 = MC / 256;

  char* ws = (char*)d_ws;
  size_t off = 0;
  ushort_t* Xc   = (ushort_t*)(ws + off); off += (size_t)MC * CC * 2;
  ushort_t* Hc   = (ushort_t*)(ws + off); off += (size_t)MC * FF * 2;
  ushort_t* w1t  = (ushort_t*)(ws + off); off += (size_t)EE * FF * CC * 2;
  ushort_t* w2t  = (ushort_t*)(ws + off); off += (size_t)EE * FF * CC * 2;
  ushort_t* y;
  if (single) {
    y = Xc;                              // alias: gemm2 writes over dead Xc
  } else {
    y = (ushort_t*)(ws + off); off += (size_t)MTOTMAX * CC * 2;
  }
  float* gwt   = (float*)(ws + off); off += (size_t)EE * 16 * CC * 4;
  int*   gids  = (int*)(ws + off);   off += (size_t)MTOTMAX * 4;
  float* gwts  = (float*)(ws + off); off += (size_t)MTOTMAX * 4;
  int*   inv   = (int*)(ws + off);   off += (size_t)65536 * 4;
  int*   re    = (int*)(ws + off);   off += (size_t)BB * LL * 2 * 4;
  float* rw    = (float*)(ws + off); off += (size_t)BB * LL * 2 * 4;
  int*   tile2e= (int*)(ws + off);   off += (size_t)NTMAX * 4;
  int*   cnt   = (int*)(ws + off);   off += 64;
  int*   cnt2  = (int*)(ws + off);   off += 64;
  int*   cntp  = (int*)(ws + off);   off += 64;
  int*   basep = (int*)(ws + off);   off += 64;

  hipMemsetAsync(cnt, 0, 128, stream);   // cnt + cnt2

  k_transpose<<<dim3(FF / 32, CC / 32, EE), 256, 0, stream>>>(w1, w1t, CC, FF); // [E][F][C]
  k_transpose<<<dim3(CC / 32, FF / 32, EE), 256, 0, stream>>>(w2, w2t, FF, CC); // [E][C][F]
  k_tgw<<<EE, 256, 0, stream>>>(gw, gwt);
  k_router<<<BB * LL, 256, 0, stream>>>(x, gwt, re, rw, cnt);
  k_pad<<<1, 256, 0, stream>>>(cnt, cntp, basep, tile2e, gids, gwts);
  k_assign<<<16, 256, 0, stream>>>(re, rw, basep, cnt2, gids, gwts, inv);

  for (int p = 0; p < npass; ++p) {
    k_gather<<<nt128, 256, 0, stream>>>(x, gids, basep, Xc, p * nt128);
    k_gemm<CC, FF, 256, true,  false><<<dim3(FF / 256, nt256), 512, 0, stream>>>(
        w1t, Xc, b1, basep, tile2e, (const float*)nullptr, Hc, p * nt256);
    k_gemm<FF, CC, 128, false, true ><<<dim3(CC / 128, nt256), 512, 0, stream>>>(
        w2t, Hc, b2, basep, tile2e, gwts, y, p * nt256);
  }
  k_final<<<BB * HH, 256, 0, stream>>>(y, inv, (float*)d_out);
}

// Round 11
// 592.865 us; speedup vs baseline: 1.2510x; 1.2510x over previous
//
#include <hip/hip_runtime.h>
#include <hip/hip_bf16.h>

#define BB   8
#define HH   64
#define WWID 64
#define CC   384
#define FF   1536
#define EE   8
#define LL   256
#define MTOTMAX 67200   // 65536 real rows + 8*192 max padding, rounded to mult of 384
#define NTMAX   352     // >= MTOTMAX/192

typedef unsigned short ushort_t;
typedef __attribute__((ext_vector_type(4))) unsigned short u16x4;
typedef __attribute__((ext_vector_type(8))) short          s16x8;  // 8 bf16 = 16B
typedef __attribute__((ext_vector_type(4))) float          f32x4;

__device__ __forceinline__ float bf2f(ushort_t u) {
  union { unsigned int i; float f; } v; v.i = ((unsigned int)u) << 16; return v.f;
}
__device__ __forceinline__ ushort_t f2bf(float f) {
  union { float f; unsigned int i; } v; v.f = f;
  unsigned int u = v.i;
  u += 0x7fffu + ((u >> 16) & 1u);
  return (ushort_t)(u >> 16);
}
// gelu via tanh-form sigmoid (proven r2/r6):
//   gelu(x) ~= x * rcp(1 + exp2(x * (-2.3022082 - 0.10294325 x^2)))
__device__ __forceinline__ float gelu_f(float x) {
  float x2 = x * x;
  float t  = __builtin_fmaf(x2, -0.10294325f, -2.3022082f);
  float e  = __builtin_amdgcn_exp2f(x * t);
  float r  = __builtin_amdgcn_rcpf(1.0f + e);
  return x * r;
}

// async 16B/lane global->LDS; LDS dest = wave-uniform base + lane*16
#define GLDS(g, l) __builtin_amdgcn_global_load_lds( \
    (const __attribute__((address_space(1))) void*)(g), \
    (__attribute__((address_space(3))) void*)(l), 16, 0, 0)

// ---------------------------------------------------------------------------
// Transpose+cast: src f32 [E][R][Cd] -> dst bf16 [E][Cd][R]
// ---------------------------------------------------------------------------
__global__ __launch_bounds__(256) void k_transpose(const float* __restrict__ src,
                                                   ushort_t* __restrict__ dst,
                                                   int R, int Cd) {
  __shared__ ushort_t tile[32][33];
  int e  = blockIdx.z;
  int c0 = blockIdx.x * 32, r0 = blockIdx.y * 32;
  int tx = threadIdx.x & 31, ty = threadIdx.x >> 5;
  const float* s = src + (size_t)e * R * Cd;
  ushort_t*    d = dst + (size_t)e * R * Cd;
  #pragma unroll
  for (int i = 0; i < 32; i += 8)
    tile[ty + i][tx] = f2bf(s[(size_t)(r0 + ty + i) * Cd + c0 + tx]);
  __syncthreads();
  #pragma unroll
  for (int i = 0; i < 32; i += 8)
    d[(size_t)(c0 + ty + i) * R + r0 + tx] = tile[tx][ty + i];
}

// ---------------------------------------------------------------------------
// gw transpose: [E][C][16] f32 -> gwt [E][16][C] f32
// ---------------------------------------------------------------------------
__global__ void k_tgw(const float* __restrict__ gw, float* __restrict__ gwt) {
  int e = blockIdx.x, t = threadIdx.x;
  for (int i = t; i < CC * 16; i += 256) {
    int c = i >> 4, p = i & 15;
    gwt[((size_t)e * 16 + p) * CC + c] = gw[(size_t)e * CC * 16 + i];
  }
}

// ---------------------------------------------------------------------------
// Router: one block per (b, conv-patch l2); coalesced f32x4; softmax -> top2.
// ---------------------------------------------------------------------------
__global__ __launch_bounds__(256) void k_router(const float* __restrict__ x,
                                                const float* __restrict__ gwt,
                                                int* __restrict__ re, float* __restrict__ rw,
                                                int* __restrict__ cnt) {
  int bid = blockIdx.x;                 // b*256 + l2
  int b = bid >> 8, l2 = bid & 255;
  int hp = l2 >> 4, wp = l2 & 15;
  int t = threadIdx.x;
  int e = t >> 5, lane = t & 31;
  const float* xb = x + (size_t)b * (HH * WWID) * CC;
  const float* ge = gwt + (size_t)e * 16 * CC;
  float acc = 0.f;
  #pragma unroll
  for (int p = 0; p < 16; ++p) {
    int pix = (hp * 4 + (p >> 2)) * 64 + wp * 4 + (p & 3);
    const float* xr = xb + (size_t)pix * CC;
    const float* gr = ge + (size_t)p * CC;
    #pragma unroll
    for (int it = 0; it < 3; ++it) {
      f32x4 xv = *reinterpret_cast<const f32x4*>(xr + it * 128 + lane * 4);
      f32x4 gv = *reinterpret_cast<const f32x4*>(gr + it * 128 + lane * 4);
      acc += xv.x * gv.x + xv.y * gv.y + xv.z * gv.z + xv.w * gv.w;
    }
  }
  #pragma unroll
  for (int d = 16; d; d >>= 1) acc += __shfl_down(acc, d, 32);
  __shared__ float logits[EE];
  if (lane == 0) logits[e] = acc;
  __syncthreads();
  if (t == 0) {
    float m = logits[0];
    #pragma unroll
    for (int i = 1; i < EE; ++i) m = fmaxf(m, logits[i]);
    float p[EE]; float s = 0.f;
    #pragma unroll
    for (int i = 0; i < EE; ++i) { p[i] = __expf(logits[i] - m); s += p[i]; }
    #pragma unroll
    for (int i = 0; i < EE; ++i) p[i] /= s;
    int e0 = 0;
    #pragma unroll
    for (int i = 1; i < EE; ++i) if (p[i] > p[e0]) e0 = i;
    int e1 = (e0 == 0) ? 1 : 0;
    #pragma unroll
    for (int i = 0; i < EE; ++i) if (i != e0 && p[i] > p[e1]) e1 = i;
    float s2 = p[e0] + p[e1] + 1e-9f;
    re[bid * 2 + 0] = e0;  re[bid * 2 + 1] = e1;
    rw[bid * 2 + 0] = p[e0] / s2;  rw[bid * 2 + 1] = p[e1] / s2;
    atomicAdd(&cnt[e0], 16);
    atomicAdd(&cnt[e1], 16);
  }
}

// ---------------------------------------------------------------------------
// Pad/prefix (parallel).  Experts padded to 192-row multiples (192-m tiles).
// ---------------------------------------------------------------------------
__global__ void k_pad(const int* __restrict__ cnt, int* __restrict__ cntp,
                      int* __restrict__ basep, int* __restrict__ tile2e,
                      int* __restrict__ gids, float* __restrict__ gwts) {
  __shared__ int s_cnt[EE], s_cntp[EE], s_base[EE + 1];
  int t = threadIdx.x;
  if (t == 0) {
    int b = 0;
    for (int e = 0; e < EE; ++e) {
      int c  = cnt[e];
      int cp = ((c + 191) / 192) * 192;      // 192 is not pow2: use div
      s_cnt[e] = c; s_cntp[e] = cp; s_base[e] = b;
      b += cp;
    }
    s_base[EE] = b;
  }
  __syncthreads();
  if (t < EE) { cntp[t] = s_cntp[t]; basep[t] = s_base[t]; }
  if (t == EE) basep[EE] = s_base[EE];
  int ntot = s_base[EE] / 192;          // 192-row tiles
  for (int g = t; g < ntot; g += 256) {
    int e = 0;
    #pragma unroll
    for (int i = 1; i < EE; ++i) if (g * 192 >= s_base[i]) e = i;
    tile2e[g] = e;
  }
  for (int e = 0; e < EE; ++e)
    for (int i = s_cnt[e] + t; i < s_cntp[e]; i += 256) {
      gids[s_base[e] + i] = -1;
      gwts[s_base[e] + i] = 0.f;
    }
}

// ---------------------------------------------------------------------------
// Assign: one thread per (patch,slot); 16 pixel rows into compacted gids/gwts
// AND inverse map inv[slot*32768+pix] = global padded row.
// ---------------------------------------------------------------------------
__global__ void k_assign(const int* __restrict__ re, const float* __restrict__ rw,
                         const int* __restrict__ basep, int* __restrict__ cnt2,
                         int* __restrict__ gids, float* __restrict__ gwts,
                         int* __restrict__ inv) {
  int i = blockIdx.x * blockDim.x + threadIdx.x;   // patch*2 + slot
  if (i >= BB * LL * 2) return;
  int pat = i >> 1, slot = i & 1;
  int b = pat >> 8, l2 = pat & 255;
  int e = re[i];
  float w = rw[i];
  int t2 = l2 >> 4, hp = l2 & 15;
  int kh = t2 >> 2, kw = t2 & 3;
  int h = hp * 4 + kh;
  int row = basep[e] + atomicAdd(&cnt2[e], 16);
  #pragma unroll
  for (int j = 0; j < 16; ++j) {
    int wpix = j * 4 + kw;
    int pix = (b << 12) + (h << 6) + wpix;
    gids[row + j] = pix;
    gwts[row + j] = w;
    inv[(slot << 15) + pix] = row + j;
  }
}

// ---------------------------------------------------------------------------
// Gather chunk: x f32 rows -> Xc bf16 [local row][CC]; t0 = pass base in
// 128-row blocks (MC is a multiple of 384, so of 128 and 192).
// ---------------------------------------------------------------------------
__global__ __launch_bounds__(256) void k_gather(const float* __restrict__ x,
                                                const int* __restrict__ gids,
                                                const int* __restrict__ basep,
                                                ushort_t* __restrict__ Xc, int t0) {
  int g = t0 + blockIdx.x;
  if (g * 128 >= basep[EE]) return;
  __shared__ int s_id[128];
  int t = threadIdx.x;
  if (t < 128) s_id[t] = gids[g * 128 + t];
  __syncthreads();
  ushort_t* dst = Xc + (size_t)blockIdx.x * 128 * CC;
  for (int i = t; i < 128 * 96; i += 256) {
    int row = i / 96, ch = (i % 96) * 4;
    int id = s_id[row];
    f32x4 v = (f32x4){0.f, 0.f, 0.f, 0.f};
    if (id >= 0) v = *reinterpret_cast<const f32x4*>(x + (size_t)(id & 32767) * CC + ch);
    u16x4 o = {f2bf(v.x), f2bf(v.y), f2bf(v.z), f2bf(v.w)};
    *reinterpret_cast<u16x4*>(dst + (size_t)row * CC + ch) = o;
  }
}

// ---------------------------------------------------------------------------
// Unified GEMM, 192x192 tile, 4 waves (256 thr), acc[6][6] per wave.
//   r10 post-mortem: per-row time invariant to blocks/CU (2.52 vs 2.56
//   ns/row at 1.5 vs 2.34 blocks/CU) -> co-resident blocks serialize on the
//   per-CU LDS READ pipe: each wave reads 8KB frags/phase; old geometry's
//   dup (A x4, B x2) gave 64KB reads per 24KB staged = 2.0 B/FLOPunit.
//   New: 2x2 wave grid, a=b=6 frags -> 36 MFMA / 12KB reads per wave
//   (3.0 MFMA/KB, 1.5x better on gemm2); acc[6][6]=144 VGPR fits the
//   256-cap at 2 waves/SIMD.  192 | 1536 and 192 | 384 -> one template.
// Schedule: proven 2-barrier phase skeleton, now 3-buffer rotation:
//   phase t: vmcnt(12) [own stage from t-3 landed; 2 groups of 6 remain]
//   -> barrier -> ds_read S(t%3) -> lgkmcnt(0) -> barrier -> stage
//   k-tile t+3 into S(t%3) -> MFMA.  Tail: vmcnt 12 / 6 / 0.
// LDS: 3 x 24KB = 72KB dynamic -> 2 blocks/CU.
// ---------------------------------------------------------------------------
#define STAGE(DST, KOFF)                                                      \
  { _Pragma("unroll")                                                         \
    for (int c = 0; c < 6; ++c)                                               \
      GLDS(src_c[c] + (KOFF), (DST) + (w * 6 + c) * 512); }

#define PHASE(VM, RD, DOST, KOFF)                                             \
  {                                                                           \
    asm volatile("s_waitcnt vmcnt(" VM ")" ::: "memory");                     \
    __builtin_amdgcn_s_barrier();                                             \
    __builtin_amdgcn_sched_barrier(0);                                        \
    s16x8 af[6], bf[6];                                                       \
    _Pragma("unroll")                                                         \
    for (int i = 0; i < 6; ++i)                                               \
      af[i] = *reinterpret_cast<const s16x8*>((RD) + (wf * 6 + i) * 512 + lane * 8); \
    _Pragma("unroll")                                                         \
    for (int j = 0; j < 6; ++j)                                               \
      bf[j] = *reinterpret_cast<const s16x8*>((RD) + (12 + wm * 6 + j) * 512 + lane * 8); \
    asm volatile("s_waitcnt lgkmcnt(0)" ::: "memory");                        \
    __builtin_amdgcn_sched_barrier(0);                                        \
    __builtin_amdgcn_s_barrier();                                             \
    if (DOST) STAGE(RD, KOFF);                                                \
    __builtin_amdgcn_s_setprio(1);                                            \
    _Pragma("unroll")                                                         \
    for (int i = 0; i < 6; ++i)                                               \
      _Pragma("unroll")                                                       \
      for (int j = 0; j < 6; ++j)                                             \
        acc[i][j] = __builtin_amdgcn_mfma_f32_16x16x32_bf16(af[i], bf[j], acc[i][j], 0, 0, 0); \
    __builtin_amdgcn_s_setprio(0);                                            \
  }

template<int K, int NOUT, bool GELU, bool OUTG>
__global__ __launch_bounds__(256, 2) void k_gemm(const ushort_t* __restrict__ A,
                                                 const ushort_t* __restrict__ Bsrc,
                                                 const float* __restrict__ bias,
                                                 const int* __restrict__ basep,
                                                 const int* __restrict__ tile2e,
                                                 const float* __restrict__ gwts,
                                                 ushort_t* __restrict__ out, int t0) {
  constexpr int NX = NOUT / 192;        // gemm1: 8, gemm2: 2
  extern __shared__ ushort_t S[];       // 3 buffers x 24 chunks x 1KB
  // bijective XCD swizzle (contiguous chunk per XCD); guarded for nwg%8!=0
  int nwg = NX * (int)gridDim.y;
  int wg  = (int)blockIdx.y * NX + (int)blockIdx.x;
  int id  = ((nwg & 7) == 0) ? ((wg & 7) * (nwg >> 3) + (wg >> 3)) : wg;
  int ng  = id % NX;                    // n-group (192 cols)
  int ly  = id / NX;                    // local 192-row tile
  int g   = t0 + ly;                    // global 192-row tile
  if (g * 192 >= basep[EE]) return;
  int e = tile2e[g];
  int t = threadIdx.x, w = t >> 6, lane = t & 63;
  int l15 = lane & 15, q = lane >> 4;
  int wf = w & 1, wm = w >> 1;          // col-half, row-half
  const ushort_t* a_src = A + ((size_t)e * NOUT + ng * 192) * K;
  const ushort_t* b_src = Bsrc + (size_t)ly * 192 * K;

  // per-wave staging sources: chunk ch = w*6+c; ch<12 -> A rows, else B rows.
  const ushort_t* src_c[6];
  #pragma unroll
  for (int c = 0; c < 6; ++c) {
    int ch = w * 6 + c;
    src_c[c] = (ch < 12)
      ? a_src + (size_t)(ch * 16 + l15) * K + q * 8
      : b_src + (size_t)((ch - 12) * 16 + l15) * K + q * 8;
  }

  f32x4 acc[6][6];
  #pragma unroll
  for (int i = 0; i < 6; ++i)
    #pragma unroll
    for (int j = 0; j < 6; ++j) acc[i][j] = (f32x4){0.f, 0.f, 0.f, 0.f};

  ushort_t* S0 = S;
  ushort_t* S1 = S + 12288;
  ushort_t* S2 = S + 24576;

  // prologue: 3 k-tiles in flight (18 GLDS per wave)
  STAGE(S0, 0);
  STAGE(S1, 32);
  STAGE(S2, 64);

  constexpr int NIT = K / 32;           // 12 or 48, divisible by 3
  for (int it = 0; it < NIT - 3; it += 3) {
    PHASE("12", S0, true, (size_t)(it + 3) * 32);
    PHASE("12", S1, true, (size_t)(it + 4) * 32);
    PHASE("12", S2, true, (size_t)(it + 5) * 32);
  }
  PHASE("12", S0, false, 0);            // phase NIT-3
  PHASE("6",  S1, false, 0);            // phase NIT-2
  PHASE("0",  S2, false, 0);            // phase NIT-1

  // epilogue
  int nb = ng * 192 + wf * 96 + q * 4;  // + i*16 + r -> output col
  f32x4 bv[6];
  #pragma unroll
  for (int i = 0; i < 6; ++i)
    bv[i] = *reinterpret_cast<const f32x4*>(bias + (size_t)e * NOUT + nb + i * 16);
  ushort_t* ob = out + (size_t)(OUTG ? g : ly) * 192 * NOUT;
  #pragma unroll
  for (int j = 0; j < 6; ++j) {
    int m = wm * 96 + j * 16 + l15;
    float wt = GELU ? 1.f : gwts[g * 192 + m];
    ushort_t* op = ob + (size_t)m * NOUT + nb;
    #pragma unroll
    for (int i = 0; i < 6; ++i) {
      u16x4 v;
      #pragma unroll
      for (int r = 0; r < 4; ++r) {
        float xv = acc[i][j][r] + bv[i][r];
        v[r] = f2bf(GELU ? gelu_f(xv) : xv * wt);
      }
      *reinterpret_cast<u16x4*>(op + i * 16) = v;
    }
  }
}

// ---------------------------------------------------------------------------
// Finalize: out[b][h][c][w] = y_c[inv0[pix]][c] + y_c[inv1[pix]][c]
// ---------------------------------------------------------------------------
__global__ __launch_bounds__(256) void k_final(const ushort_t* __restrict__ y,
                                               const int* __restrict__ inv,
                                               float* __restrict__ out) {
  int bid = blockIdx.x;                 // b*64 + h
  __shared__ float tile[64][193];
  __shared__ int s_r0[64], s_r1[64];
  int t = threadIdx.x;
  if (t < 64) {
    s_r0[t] = inv[(bid << 6) + t];
    s_r1[t] = inv[32768 + (bid << 6) + t];
  }
  __syncthreads();
  float* dst = out + (size_t)bid * CC * WWID;   // [c][w]
  #pragma unroll
  for (int half = 0; half < 2; ++half) {
    int c0 = half * 192;
    for (int i = t; i < 64 * 48; i += 256) {
      int w = i / 48, c4 = (i % 48) * 4;
      u16x4 a = *reinterpret_cast<const u16x4*>(y + (size_t)s_r0[w] * CC + c0 + c4);
      u16x4 b = *reinterpret_cast<const u16x4*>(y + (size_t)s_r1[w] * CC + c0 + c4);
      #pragma unroll
      for (int k = 0; k < 4; ++k)
        tile[w][c4 + k] = bf2f(a[k]) + bf2f(b[k]);
    }
    __syncthreads();
    for (int i = t; i < 64 * 192; i += 256) {
      int cl = i / 64, w = i % 64;
      dst[(size_t)(c0 + cl) * WWID + w] = tile[w][cl];
    }
    __syncthreads();
  }
}

// ---------------------------------------------------------------------------
extern "C" void kernel_launch(void* const* d_in, const int* in_sizes, int n_in,
                              void* d_out, int out_size, void* d_ws, size_t ws_size,
                              hipStream_t stream) {
  const float* x  = (const float*)d_in[0];
  const float* gw = (const float*)d_in[1];
  const float* w1 = (const float*)d_in[2];
  const float* b1 = (const float*)d_in[3];
  const float* w2 = (const float*)d_in[4];
  const float* b2 = (const float*)d_in[5];

  // fixed buffers excluding Xc / Hc
  const size_t fixed2 = (size_t)EE * FF * CC * 2 * 2   // w1t, w2t
                      + (size_t)MTOTMAX * CC * 2        // y
                      + (size_t)EE * 16 * CC * 4        // gwt
                      + (size_t)MTOTMAX * 4 * 2         // gids,gwts
                      + (size_t)65536 * 4               // inv
                      + (size_t)BB * LL * 2 * 4 * 2     // re, rw
                      + (size_t)NTMAX * 4               // tile2e
                      + 1024;
  // MC candidates: multiples of 384 (lcm of 128-gather and 192-gemm tiles)
  const int cands[4] = {33792, 16896, 8448, 4224};
  int MC = 4224;
  for (int i = 0; i < 4; ++i)
    if (fixed2 + (size_t)cands[i] * 3840 <= ws_size) { MC = cands[i]; break; }
  const int npass = (MTOTMAX + MC - 1) / MC;
  const int nt128 = MC / 128;
  const int ntg   = MC / 192;

  char* ws = (char*)d_ws;
  size_t off = 0;
  ushort_t* Xc   = (ushort_t*)(ws + off); off += (size_t)MC * CC * 2;
  ushort_t* Hc   = (ushort_t*)(ws + off); off += (size_t)MC * FF * 2;
  ushort_t* w1t  = (ushort_t*)(ws + off); off += (size_t)EE * FF * CC * 2;
  ushort_t* w2t  = (ushort_t*)(ws + off); off += (size_t)EE * FF * CC * 2;
  ushort_t* y    = (ushort_t*)(ws + off); off += (size_t)MTOTMAX * CC * 2;
  float* gwt   = (float*)(ws + off); off += (size_t)EE * 16 * CC * 4;
  int*   gids  = (int*)(ws + off);   off += (size_t)MTOTMAX * 4;
  float* gwts  = (float*)(ws + off); off += (size_t)MTOTMAX * 4;
  int*   inv   = (int*)(ws + off);   off += (size_t)65536 * 4;
  int*   re    = (int*)(ws + off);   off += (size_t)BB * LL * 2 * 4;
  float* rw    = (float*)(ws + off); off += (size_t)BB * LL * 2 * 4;
  int*   tile2e= (int*)(ws + off);   off += (size_t)NTMAX * 4;
  int*   cnt   = (int*)(ws + off);   off += 64;
  int*   cnt2  = (int*)(ws + off);   off += 64;
  int*   cntp  = (int*)(ws + off);   off += 64;
  int*   basep = (int*)(ws + off);   off += 64;

  hipMemsetAsync(cnt, 0, 128, stream);   // cnt + cnt2

  k_transpose<<<dim3(FF / 32, CC / 32, EE), 256, 0, stream>>>(w1, w1t, CC, FF); // [E][F][C]
  k_transpose<<<dim3(CC / 32, FF / 32, EE), 256, 0, stream>>>(w2, w2t, FF, CC); // [E][C][F]
  k_tgw<<<EE, 256, 0, stream>>>(gw, gwt);
  k_router<<<BB * LL, 256, 0, stream>>>(x, gwt, re, rw, cnt);
  k_pad<<<1, 256, 0, stream>>>(cnt, cntp, basep, tile2e, gids, gwts);
  k_assign<<<16, 256, 0, stream>>>(re, rw, basep, cnt2, gids, gwts, inv);

  const int shmem = 3 * 24 * 1024;       // 72KB (3-buffer x 24 chunks)
  for (int p = 0; p < npass; ++p) {
    k_gather<<<nt128, 256, 0, stream>>>(x, gids, basep, Xc, p * nt128);
    k_gemm<CC, FF, true,  false><<<dim3(FF / 192, ntg), 256, shmem, stream>>>(
        w1t, Xc, b1, basep, tile2e, (const float*)nullptr, Hc, p * ntg);
    k_gemm<FF, CC, false, true ><<<dim3(CC / 192, ntg), 256, shmem, stream>>>(
        w2t, Hc, b2, basep, tile2e, gwts, y, p * ntg);
  }
  k_final<<<BB * HH, 256, 0, stream>>>(y, inv, (float*)d_out);
}